// Round 1
// baseline (316.902 us; speedup 1.0000x reference)
//
#include <hip/hip_runtime.h>
#include <hip/hip_bf16.h>
#include <stdint.h>

// Problem constants (reference: B=8, T=2048, C=1024 (n_embd), H=128 (head dim))
#define BB 8
#define TT 2048
#define CC 1024
#define HH 128

// MFMA fragment types per cdna_hip_programming.md §3 (compile-verified on gfx950)
typedef __attribute__((ext_vector_type(8))) short bf16x8;           // 8 bf16 (4 VGPRs)
typedef __attribute__((ext_vector_type(8))) unsigned short u16x8;
typedef __attribute__((ext_vector_type(4))) float f32x4;            // 4 fp32 acc

static __device__ __forceinline__ unsigned short f2bf(float f) {
    union { float f; uint32_t u; } v; v.f = f;
    // round-to-nearest-even fp32 -> bf16
    return (unsigned short)((v.u + 0x7fffu + ((v.u >> 16) & 1u)) >> 16);
}

// ---------------------------------------------------------------------------
// Kernel 1: QKV projection GEMM. C-tile 128m x 64n, BK=32, fp32->bf16 in staging.
// Output: Q,K row-major bf16 [B*T][128]; V transposed bf16 [B][128][T].
// grid = (128, 6): blockIdx.x = m-tile, blockIdx.y = n-tile (2 per matrix).
// ---------------------------------------------------------------------------
__global__ __launch_bounds__(256) void qkv_proj(
    const float* __restrict__ x, const float* __restrict__ Wq,
    const float* __restrict__ Wk, const float* __restrict__ Wv,
    unsigned short* __restrict__ Q, unsigned short* __restrict__ K,
    unsigned short* __restrict__ Vt)
{
    __shared__ unsigned short As[128 * 32];   // [m][k], k contiguous (A-frag reads)
    __shared__ unsigned short Bs[64 * 32];    // [n][k], k contiguous (B-frag reads)

    const int bm = blockIdx.x;              // 0..127
    const int bn = blockIdx.y;              // 0..5
    const int mat = bn >> 1;                // 0=Q 1=K 2=V
    const float* __restrict__ W = (mat == 0) ? Wq : ((mat == 1) ? Wk : Wv);
    const int n0 = (bn & 1) * 64;           // col offset inside W (H=128)
    const int m0 = bm * 128;

    const int tid  = threadIdx.x;
    const int lane = tid & 63;
    const int wave = tid >> 6;              // 4 waves, each owns 32 m-rows
    const int qd = lane >> 4;               // quad
    const int ln = lane & 15;

    f32x4 acc[2][4];
    #pragma unroll
    for (int i = 0; i < 2; i++)
        #pragma unroll
        for (int j = 0; j < 4; j++) acc[i][j] = (f32x4){0.f, 0.f, 0.f, 0.f};

    const int ar = tid >> 2;                // 0..63 (staging row, x)
    const int ac = (tid & 3) << 3;          // 0,8,16,24 (staging col, x)
    const int bk = tid >> 3;                // 0..31 (staging k, W)
    const int bc = (tid & 7) << 3;          // 0..56 (staging n, W)

    for (int k0 = 0; k0 < CC; k0 += 32) {
        // stage x (fp32) -> As (bf16), 128 rows x 32 k
        #pragma unroll
        for (int h = 0; h < 2; h++) {
            int r = ar + h * 64;
            const float* src = x + (size_t)(m0 + r) * CC + k0 + ac;
            float4 f0 = *(const float4*)(src);
            float4 f1 = *(const float4*)(src + 4);
            u16x8 vv;
            vv[0] = f2bf(f0.x); vv[1] = f2bf(f0.y); vv[2] = f2bf(f0.z); vv[3] = f2bf(f0.w);
            vv[4] = f2bf(f1.x); vv[5] = f2bf(f1.y); vv[6] = f2bf(f1.z); vv[7] = f2bf(f1.w);
            *(u16x8*)(&As[r * 32 + ac]) = vv;
        }
        // stage W (fp32, [k][n]) -> Bs (bf16, [n][k] transposed)
        {
            const float* src = W + (size_t)(k0 + bk) * HH + n0 + bc;
            float4 f0 = *(const float4*)(src);
            float4 f1 = *(const float4*)(src + 4);
            Bs[(bc + 0) * 32 + bk] = f2bf(f0.x);
            Bs[(bc + 1) * 32 + bk] = f2bf(f0.y);
            Bs[(bc + 2) * 32 + bk] = f2bf(f0.z);
            Bs[(bc + 3) * 32 + bk] = f2bf(f0.w);
            Bs[(bc + 4) * 32 + bk] = f2bf(f1.x);
            Bs[(bc + 5) * 32 + bk] = f2bf(f1.y);
            Bs[(bc + 6) * 32 + bk] = f2bf(f1.z);
            Bs[(bc + 7) * 32 + bk] = f2bf(f1.w);
        }
        __syncthreads();
        // A-frag: A[m=ln][k=qd*8+j]; B-frag: B[k=qd*8+j][n=ln]
        bf16x8 a0 = *(const bf16x8*)&As[(wave * 32 + ln) * 32 + qd * 8];
        bf16x8 a1 = *(const bf16x8*)&As[(wave * 32 + 16 + ln) * 32 + qd * 8];
        #pragma unroll
        for (int nf = 0; nf < 4; nf++) {
            bf16x8 b = *(const bf16x8*)&Bs[(nf * 16 + ln) * 32 + qd * 8];
            acc[0][nf] = __builtin_amdgcn_mfma_f32_16x16x32_bf16(a0, b, acc[0][nf], 0, 0, 0);
            acc[1][nf] = __builtin_amdgcn_mfma_f32_16x16x32_bf16(a1, b, acc[1][nf], 0, 0, 0);
        }
        __syncthreads();
    }

    // epilogue: C/D layout row = qd*4+r, col = ln (within each 16x16 frag)
    #pragma unroll
    for (int half = 0; half < 2; half++) {
        #pragma unroll
        for (int nf = 0; nf < 4; nf++) {
            int h = n0 + nf * 16 + ln;            // 0..127 within matrix
            #pragma unroll
            for (int r = 0; r < 4; r++) {
                int m = m0 + wave * 32 + half * 16 + qd * 4 + r;   // global row
                unsigned short val = f2bf(acc[half][nf][r]);
                if (mat == 0)      Q[(size_t)m * HH + h] = val;
                else if (mat == 1) K[(size_t)m * HH + h] = val;
                else {
                    int b = m >> 11, t = m & (TT - 1);
                    Vt[((size_t)b * HH + h) * TT + t] = val;   // scattered; L2 merges
                }
            }
        }
    }
}

// ---------------------------------------------------------------------------
// Kernel 2: flash attention (causal). One wave = 16 query rows; K-tile = 32.
// S=Q·K^T via mfma_16x16x32 (2 col-frags x 4 k-chunks); online softmax in
// exp2 domain; P -> LDS (C-layout -> A-layout round trip); O += P·V (8 h-frags).
// grid = 256 blocks x 256 thr; block bx: batch = bx>>5, j = bx&31, wave w
// handles q-tile {j, 63-j, 64+j, 127-j}[w] (per-block work sum is constant).
// ---------------------------------------------------------------------------
__global__ __launch_bounds__(256) void attn(
    const unsigned short* __restrict__ Q, const unsigned short* __restrict__ K,
    const unsigned short* __restrict__ Vt, float* __restrict__ out)
{
    __shared__ unsigned short Ps[4][16 * 32];   // per-wave P tile, pitch 32

    const int tid  = threadIdx.x;
    const int lane = tid & 63;
    const int wave = tid >> 6;
    const int qd = lane >> 4;
    const int ln = lane & 15;

    const int bx = blockIdx.x;
    const int b  = bx >> 5;          // batch
    const int j  = bx & 31;
    const int idx = (wave == 0) ? j : (wave == 1) ? (63 - j)
                  : (wave == 2) ? (64 + j) : (127 - j);
    const int qbase = idx * 16;      // query rows [qbase, qbase+16) in batch b

    const unsigned short* Qb = Q  + (size_t)b * TT * HH;
    const unsigned short* Kb = K  + (size_t)b * TT * HH;
    const unsigned short* Vb = Vt + (size_t)b * HH * TT;

    // Q A-frags: 4 k-chunks of 32 channels
    bf16x8 aq[4];
    #pragma unroll
    for (int c = 0; c < 4; c++)
        aq[c] = *(const bf16x8*)(Qb + (size_t)(qbase + ln) * HH + c * 32 + qd * 8);

    float m2[4], l[4];               // running max (log2 domain) and denom, per owned row
    f32x4 O[8];                      // O accum, C-layout, 8 h-frags of 16
    #pragma unroll
    for (int r = 0; r < 4; r++) { m2[r] = -1e30f; l[r] = 0.f; }
    #pragma unroll
    for (int h = 0; h < 8; h++) O[h] = (f32x4){0.f, 0.f, 0.f, 0.f};

    const float sl = 0.08838834764831843f * 1.4426950408889634f; // (1/sqrt(128))*log2(e)
    unsigned short* ps = Ps[wave];

    for (int s0 = 0; s0 < qbase + 16; s0 += 32) {
        // ---- S = Q K^T (raw logits), 16 q x 32 keys ----
        f32x4 s[2] = {(f32x4){0.f,0.f,0.f,0.f}, (f32x4){0.f,0.f,0.f,0.f}};
        #pragma unroll
        for (int nt = 0; nt < 2; nt++) {
            const unsigned short* kp = Kb + (size_t)(s0 + nt * 16 + ln) * HH + qd * 8;
            #pragma unroll
            for (int c = 0; c < 4; c++) {
                bf16x8 bk = *(const bf16x8*)(kp + c * 32);
                s[nt] = __builtin_amdgcn_mfma_f32_16x16x32_bf16(aq[c], bk, s[nt], 0, 0, 0);
            }
        }
        // ---- scale to log2 domain + causal mask ----
        float x2[2][4];
        #pragma unroll
        for (int nt = 0; nt < 2; nt++) {
            int col = s0 + nt * 16 + ln;
            #pragma unroll
            for (int r = 0; r < 4; r++) {
                int row = qbase + qd * 4 + r;
                x2[nt][r] = (col <= row) ? s[nt][r] * sl : -1e30f;
            }
        }
        // ---- online softmax per owned row (rows live across 16 lanes of a quad) ----
        float p0[4], p1[4], alpha[4];
        #pragma unroll
        for (int r = 0; r < 4; r++) {
            float mx = fmaxf(x2[0][r], x2[1][r]);
            #pragma unroll
            for (int off = 1; off < 16; off <<= 1)
                mx = fmaxf(mx, __shfl_xor(mx, off, 64));
            float mn = fmaxf(m2[r], mx);
            alpha[r] = exp2f(m2[r] - mn);
            m2[r] = mn;
            p0[r] = exp2f(x2[0][r] - mn);
            p1[r] = exp2f(x2[1][r] - mn);
            float sum = p0[r] + p1[r];
            #pragma unroll
            for (int off = 1; off < 16; off <<= 1)
                sum += __shfl_xor(sum, off, 64);
            l[r] = l[r] * alpha[r] + sum;
        }
        // ---- P (C-layout) -> LDS bf16 ----
        #pragma unroll
        for (int r = 0; r < 4; r++) {
            ps[(qd * 4 + r) * 32 + ln]      = f2bf(p0[r]);
            ps[(qd * 4 + r) * 32 + 16 + ln] = f2bf(p1[r]);
        }
        // ---- rescale O ----
        #pragma unroll
        for (int h = 0; h < 8; h++)
            #pragma unroll
            for (int r = 0; r < 4; r++) O[h][r] *= alpha[r];
        // compiler memory fence: keep ds_reads after the P stores (same-wave DS is in-order in HW)
        asm volatile("" ::: "memory");
        bf16x8 ap = *(const bf16x8*)(ps + ln * 32 + qd * 8);   // A[m=ln][k=qd*8+j]
        asm volatile("" ::: "memory");
        // ---- O += P V : B[k=s][n=h] from Vt rows (contiguous in s) ----
        #pragma unroll
        for (int ht = 0; ht < 8; ht++) {
            bf16x8 bv = *(const bf16x8*)(Vb + (size_t)(ht * 16 + ln) * TT + s0 + qd * 8);
            O[ht] = __builtin_amdgcn_mfma_f32_16x16x32_bf16(ap, bv, O[ht], 0, 0, 0);
        }
    }

    // ---- epilogue: O / l -> out (fp32) ----
    float inv[4];
    #pragma unroll
    for (int r = 0; r < 4; r++) inv[r] = 1.0f / l[r];
    float* ob = out + (size_t)b * TT * HH;
    #pragma unroll
    for (int ht = 0; ht < 8; ht++)
        #pragma unroll
        for (int r = 0; r < 4; r++)
            ob[(size_t)(qbase + qd * 4 + r) * HH + ht * 16 + ln] = O[ht][r] * inv[r];
}

// ---------------------------------------------------------------------------
extern "C" void kernel_launch(void* const* d_in, const int* in_sizes, int n_in,
                              void* d_out, int out_size, void* d_ws, size_t ws_size,
                              hipStream_t stream) {
    const float* x  = (const float*)d_in[0];
    const float* Wq = (const float*)d_in[1];
    const float* Wk = (const float*)d_in[2];
    const float* Wv = (const float*)d_in[3];

    // workspace: Q, K row-major bf16 [B*T][H]; Vt bf16 [B][H][T]  (12.6 MB total)
    unsigned short* Qw = (unsigned short*)d_ws;
    unsigned short* Kw = Qw + (size_t)BB * TT * HH;
    unsigned short* Vw = Kw + (size_t)BB * TT * HH;

    qkv_proj<<<dim3(128, 6), 256, 0, stream>>>(x, Wq, Wk, Wv, Qw, Kw, Vw);
    attn<<<dim3(256), 256, 0, stream>>>(Qw, Kw, Vw, (float*)d_out);
}

// Round 2
// 200.609 us; speedup vs baseline: 1.5797x; 1.5797x over previous
//
#include <hip/hip_runtime.h>
#include <hip/hip_bf16.h>
#include <stdint.h>

// Problem constants: B=8, T=2048, C=1024 (n_embd), H=128 (head dim)
#define BB 8
#define TT 2048
#define CC 1024
#define HH 128

typedef __attribute__((ext_vector_type(8))) short bf16x8;           // 8 bf16 (4 VGPRs)
typedef __attribute__((ext_vector_type(8))) unsigned short u16x8;
typedef __attribute__((ext_vector_type(4))) float f32x4;            // 4 fp32 acc

static __device__ __forceinline__ unsigned short f2bf(float f) {
    union { float f; uint32_t u; } v; v.f = f;
    return (unsigned short)((v.u + 0x7fffu + ((v.u >> 16) & 1u)) >> 16);  // RNE
}

#define GLOBAL_AS __attribute__((address_space(1)))
#define LDS_AS    __attribute__((address_space(3)))
static __device__ __forceinline__ void async16(const void* g, void* l) {
    // direct global->LDS DMA, 16B/lane; LDS dest = wave-uniform base + lane*16
    __builtin_amdgcn_global_load_lds((const GLOBAL_AS void*)g, (LDS_AS void*)l, 16, 0, 0);
}

// swizzled 16B-chunk slot for a [row][8 chunks-of-8-k] LDS tile: kills frag-read bank conflicts
#define SW(row, kc) (((row) << 3) + (((kc) ^ ((row) & 7))))

// ---------------------------------------------------------------------------
// Kernel 0: convert x (fp32->bf16, row-major) and W (fp32 [k][n] -> bf16 [mat][n][k])
// ---------------------------------------------------------------------------
#define NXC (BB*TT*CC/8)     // 2,097,152 groups of 8
__global__ __launch_bounds__(256) void convert_k(
    const float* __restrict__ x, const float* __restrict__ Wq,
    const float* __restrict__ Wk, const float* __restrict__ Wv,
    unsigned short* __restrict__ xb, unsigned short* __restrict__ Wb)
{
    int gid = blockIdx.x * 256 + threadIdx.x;
    if (gid < NXC) {
        const float* src = x + (size_t)gid * 8;
        float4 f0 = *(const float4*)(src);
        float4 f1 = *(const float4*)(src + 4);
        u16x8 v;
        v[0]=f2bf(f0.x); v[1]=f2bf(f0.y); v[2]=f2bf(f0.z); v[3]=f2bf(f0.w);
        v[4]=f2bf(f1.x); v[5]=f2bf(f1.y); v[6]=f2bf(f1.z); v[7]=f2bf(f1.w);
        *(u16x8*)(xb + (size_t)gid * 8) = v;
    } else {
        int u = gid - NXC;                    // 0 .. 3*128*128-1
        if (u >= 3 * 128 * 128) return;
        int kc = u & 127, n = (u >> 7) & 127, mat = u >> 14;
        const float* W = (mat == 0) ? Wq : (mat == 1) ? Wk : Wv;
        const float* s = W + (size_t)(kc * 8) * HH + n;
        u16x8 v;
        #pragma unroll
        for (int j = 0; j < 8; j++) v[j] = f2bf(s[(size_t)j * HH]);
        *(u16x8*)(Wb + ((size_t)mat * HH + n) * CC + kc * 8) = v;
    }
}

// ---------------------------------------------------------------------------
// Kernel 1: QKV GEMM. C-tile 64m x 128n, BK=64, global_load_lds(16B) staging
// with XOR-swizzled LDS. grid = (256 m-tiles, 3 matrices). Epilogue goes
// through LDS for coalesced writes; V is transposed to Vt[b][h][t].
// ---------------------------------------------------------------------------
__global__ __launch_bounds__(256) void qkv_gemm(
    const unsigned short* __restrict__ xb, const unsigned short* __restrict__ Wb,
    unsigned short* __restrict__ Q, unsigned short* __restrict__ K,
    unsigned short* __restrict__ Vt)
{
    // staging: As slots 0..511 (64 rows x 8 kc), Bs slots 512..1535 (128 rows x 8 kc)
    // epilogue reuses as [row][136] u16 transpose buffer (needs 17408 u16)
    __shared__ unsigned short lds[17408];

    const int mt  = blockIdx.x;        // 0..255
    const int mat = blockIdx.y;        // 0=Q 1=K 2=V
    const int m0  = mt * 64;

    const int tid  = threadIdx.x;
    const int lane = tid & 63;
    const int w    = tid >> 6;
    const int qd   = lane >> 4;
    const int ln   = lane & 15;
    const int wm   = w & 1, wn = w >> 1;

    f32x4 acc[2][4];
    #pragma unroll
    for (int i = 0; i < 2; i++)
        #pragma unroll
        for (int j = 0; j < 4; j++) acc[i][j] = (f32x4){0.f,0.f,0.f,0.f};

    const unsigned short* Wm = Wb + (size_t)mat * HH * CC;

    for (int k0 = 0; k0 < CC; k0 += 64) {
        #pragma unroll
        for (int i = 0; i < 6; i++) {
            int sb = (i * 4 + w) * 64;          // wave-uniform slot base
            int c  = sb + lane;
            if (i < 2) {                         // As: x tile 64x64
                int row = c >> 3, kc = (c & 7) ^ (row & 7);
                async16(xb + (size_t)(m0 + row) * CC + k0 + kc * 8,
                        &lds[(size_t)sb * 8]);
            } else {                             // Bs: W tile 128x64
                int c2 = c - 512;
                int row = c2 >> 3, kc = (c2 & 7) ^ (row & 7);
                async16(Wm + (size_t)row * CC + k0 + kc * 8,
                        &lds[(size_t)sb * 8]);
            }
        }
        __syncthreads();                         // compiler drains vmcnt before barrier
        #pragma unroll
        for (int ks = 0; ks < 2; ks++) {
            bf16x8 a[2], b[4];
            #pragma unroll
            for (int mf = 0; mf < 2; mf++)
                a[mf] = *(const bf16x8*)&lds[(size_t)SW(wm*32 + mf*16 + ln, ks*4 + qd) * 8];
            #pragma unroll
            for (int nf = 0; nf < 4; nf++)
                b[nf] = *(const bf16x8*)&lds[(size_t)(512 + SW(wn*64 + nf*16 + ln, ks*4 + qd)) * 8];
            #pragma unroll
            for (int mf = 0; mf < 2; mf++)
                #pragma unroll
                for (int nf = 0; nf < 4; nf++)
                    acc[mf][nf] = __builtin_amdgcn_mfma_f32_16x16x32_bf16(a[mf], b[nf], acc[mf][nf], 0, 0, 0);
        }
        __syncthreads();
    }

    // epilogue: acc -> LDS (Q/K: [row][col]; V: [col_h][row_t]) -> coalesced dump
    #pragma unroll
    for (int mf = 0; mf < 2; mf++)
        #pragma unroll
        for (int nf = 0; nf < 4; nf++)
            #pragma unroll
            for (int r = 0; r < 4; r++) {
                int rrow = wm*32 + mf*16 + qd*4 + r;     // 0..63 (t within tile)
                int ccol = wn*64 + nf*16 + ln;           // 0..127 (h)
                unsigned short v = f2bf(acc[mf][nf][r]);
                if (mat < 2) lds[rrow * 136 + ccol] = v;
                else         lds[ccol * 136 + rrow] = v;
            }
    __syncthreads();
    if (mat < 2) {
        unsigned short* dst = (mat == 0) ? Q : K;
        #pragma unroll
        for (int i = 0; i < 4; i++) {
            int cidx = i * 256 + tid;                    // 64 rows x 16 chunks
            int rr = cidx >> 4, cc = (cidx & 15) * 8;
            u16x8 v = *(const u16x8*)&lds[rr * 136 + cc];
            *(u16x8*)(dst + (size_t)(m0 + rr) * HH + cc) = v;
        }
    } else {
        int bb = m0 >> 11, t0 = m0 & (TT - 1);
        #pragma unroll
        for (int i = 0; i < 4; i++) {
            int cidx = i * 256 + tid;                    // 128 h-rows x 8 chunks
            int rr = cidx >> 3, cc = (cidx & 7) * 8;
            u16x8 v = *(const u16x8*)&lds[rr * 136 + cc];
            *(u16x8*)(Vt + ((size_t)bb * HH + rr) * TT + t0 + cc) = v;
        }
    }
}

// ---------------------------------------------------------------------------
// Kernel 2: flash attention (causal), block-level key-split.
// grid = 1024 blocks (8 batches x 128 q-tiles, longest-first), 4 waves/block.
// Wave v handles key-steps v, v+4, ... of its q-tile; partial (m,l,O) merged
// through LDS at the end. 16 q-rows per tile, 32 keys per step.
// ---------------------------------------------------------------------------
__global__ __launch_bounds__(256, 4) void attn(
    const unsigned short* __restrict__ Q, const unsigned short* __restrict__ K,
    const unsigned short* __restrict__ Vt, float* __restrict__ out)
{
    __shared__ float Os[4][16 * 132];            // partial O, padded pitch (33.8KB)
    __shared__ float Ml[2][4][16];               // [m|l][wave][row]
    __shared__ unsigned short Ps[4][16 * 40];    // P tiles, pitch 40 (5KB)

    const int tid  = threadIdx.x;
    const int lane = tid & 63;
    const int wave = tid >> 6;
    const int qd = lane >> 4;
    const int ln = lane & 15;

    const int bx = blockIdx.x;
    const int qt = 127 - (bx >> 3);              // longest q-tiles dispatched first
    const int b  = bx & 7;
    const int qbase = qt * 16;
    const int nst = (qt + 2) >> 1;               // ceil(16(qt+1)/32)

    const unsigned short* Qb = Q  + (size_t)b * TT * HH;
    const unsigned short* Kb = K  + (size_t)b * TT * HH;
    const unsigned short* Vb = Vt + (size_t)b * HH * TT;

    bf16x8 aq[4];
    #pragma unroll
    for (int c = 0; c < 4; c++)
        aq[c] = *(const bf16x8*)(Qb + (size_t)(qbase + ln) * HH + c * 32 + qd * 8);

    float m2[4], l[4];
    f32x4 O[8];
    #pragma unroll
    for (int r = 0; r < 4; r++) { m2[r] = -1e30f; l[r] = 0.f; }
    #pragma unroll
    for (int h = 0; h < 8; h++) O[h] = (f32x4){0.f,0.f,0.f,0.f};

    const float sl = 0.08838834764831843f * 1.4426950408889634f; // (1/sqrt(128))*log2e
    unsigned short* ps = Ps[wave];

    for (int st = wave; st < nst; st += 4) {
        const int s0 = st * 32;
        // ---- S = Q K^T, 16q x 32 keys ----
        f32x4 s[2] = {(f32x4){0.f,0.f,0.f,0.f}, (f32x4){0.f,0.f,0.f,0.f}};
        const unsigned short* kp0 = Kb + (size_t)(s0 + ln) * HH + qd * 8;
        const unsigned short* kp1 = kp0 + 16 * HH;
        #pragma unroll
        for (int c = 0; c < 4; c++) {
            s[0] = __builtin_amdgcn_mfma_f32_16x16x32_bf16(aq[c], *(const bf16x8*)(kp0 + c*32), s[0], 0, 0, 0);
            s[1] = __builtin_amdgcn_mfma_f32_16x16x32_bf16(aq[c], *(const bf16x8*)(kp1 + c*32), s[1], 0, 0, 0);
        }
        // ---- scale (log2 domain) + causal mask ----
        float x2[2][4];
        #pragma unroll
        for (int nt = 0; nt < 2; nt++) {
            int col = s0 + nt * 16 + ln;
            #pragma unroll
            for (int r = 0; r < 4; r++) {
                int row = qbase + qd * 4 + r;
                x2[nt][r] = (col <= row) ? s[nt][r] * sl : -1e30f;
            }
        }
        // ---- online softmax (row lives across 16 ln lanes) ----
        float p0[4], p1[4], alpha[4];
        #pragma unroll
        for (int r = 0; r < 4; r++) {
            float mx = fmaxf(x2[0][r], x2[1][r]);
            #pragma unroll
            for (int off = 1; off < 16; off <<= 1)
                mx = fmaxf(mx, __shfl_xor(mx, off, 64));
            float mn = fmaxf(m2[r], mx);
            alpha[r] = __builtin_amdgcn_exp2f(m2[r] - mn);
            m2[r] = mn;
            p0[r] = __builtin_amdgcn_exp2f(x2[0][r] - mn);
            p1[r] = __builtin_amdgcn_exp2f(x2[1][r] - mn);
            float sum = p0[r] + p1[r];
            #pragma unroll
            for (int off = 1; off < 16; off <<= 1)
                sum += __shfl_xor(sum, off, 64);
            l[r] = l[r] * alpha[r] + sum;
        }
        // ---- P (C-layout) -> LDS bf16, padded pitch 40 ----
        #pragma unroll
        for (int r = 0; r < 4; r++) {
            ps[(qd * 4 + r) * 40 + ln]      = f2bf(p0[r]);
            ps[(qd * 4 + r) * 40 + 16 + ln] = f2bf(p1[r]);
        }
        // ---- rescale O ----
        #pragma unroll
        for (int h = 0; h < 8; h++)
            #pragma unroll
            for (int r = 0; r < 4; r++) O[h][r] *= alpha[r];
        // P in A-layout (same-wave DS ordering; compiler keeps order via aliasing)
        bf16x8 ap = *(const bf16x8*)(ps + ln * 40 + qd * 8);
        // ---- O += P V ----
        #pragma unroll
        for (int ht = 0; ht < 8; ht++) {
            bf16x8 bv = *(const bf16x8*)(Vb + (size_t)(ht * 16 + ln) * TT + s0 + qd * 8);
            O[ht] = __builtin_amdgcn_mfma_f32_16x16x32_bf16(ap, bv, O[ht], 0, 0, 0);
        }
    }

    // ---- merge 4 per-wave partials through LDS ----
    if (ln == 0) {
        #pragma unroll
        for (int r = 0; r < 4; r++) {
            Ml[0][wave][qd * 4 + r] = m2[r];
            Ml[1][wave][qd * 4 + r] = l[r];
        }
    }
    __syncthreads();
    float fsc[4];
    #pragma unroll
    for (int r = 0; r < 4; r++) {
        int row = qd * 4 + r;
        float M = fmaxf(fmaxf(Ml[0][0][row], Ml[0][1][row]),
                        fmaxf(Ml[0][2][row], Ml[0][3][row]));
        fsc[r] = __builtin_amdgcn_exp2f(m2[r] - M);
    }
    #pragma unroll
    for (int ht = 0; ht < 8; ht++)
        #pragma unroll
        for (int r = 0; r < 4; r++)
            Os[wave][(qd * 4 + r) * 132 + ht * 16 + ln] = O[ht][r] * fsc[r];
    __syncthreads();

    // ---- cooperative readback: thread -> (row, 8 h) ----
    {
        int row = tid >> 4, h0 = (tid & 15) * 8;
        float M = fmaxf(fmaxf(Ml[0][0][row], Ml[0][1][row]),
                        fmaxf(Ml[0][2][row], Ml[0][3][row]));
        float L = Ml[1][0][row] * __builtin_amdgcn_exp2f(Ml[0][0][row] - M)
                + Ml[1][1][row] * __builtin_amdgcn_exp2f(Ml[0][1][row] - M)
                + Ml[1][2][row] * __builtin_amdgcn_exp2f(Ml[0][2][row] - M)
                + Ml[1][3][row] * __builtin_amdgcn_exp2f(Ml[0][3][row] - M);
        float inv = 1.0f / L;
        float o[8];
        #pragma unroll
        for (int j = 0; j < 8; j++) o[j] = 0.f;
        #pragma unroll
        for (int wv = 0; wv < 4; wv++) {
            const float* p = &Os[wv][row * 132 + h0];
            #pragma unroll
            for (int j = 0; j < 8; j++) o[j] += p[j];
        }
        float* op = out + ((size_t)b * TT + qbase + row) * HH + h0;
        float4 v0 = {o[0]*inv, o[1]*inv, o[2]*inv, o[3]*inv};
        float4 v1 = {o[4]*inv, o[5]*inv, o[6]*inv, o[7]*inv};
        ((float4*)op)[0] = v0;
        ((float4*)op)[1] = v1;
    }
}

// ---------------------------------------------------------------------------
extern "C" void kernel_launch(void* const* d_in, const int* in_sizes, int n_in,
                              void* d_out, int out_size, void* d_ws, size_t ws_size,
                              hipStream_t stream) {
    const float* x  = (const float*)d_in[0];
    const float* Wq = (const float*)d_in[1];
    const float* Wk = (const float*)d_in[2];
    const float* Wv = (const float*)d_in[3];

    // workspace layout (bf16 u16 elements):
    //   xb [B*T][C]           = 16,777,216 elems (33.6MB)
    //   Wb [3][H][C]          =    393,216 elems (0.8MB)
    //   Q,K [B*T][H]          =  2,097,152 each  (4.2MB each)
    //   Vt [B][H][T]          =  2,097,152       (4.2MB)
    unsigned short* xb = (unsigned short*)d_ws;
    unsigned short* Wb = xb + (size_t)BB * TT * CC;
    unsigned short* Qw = Wb + (size_t)3 * HH * CC;
    unsigned short* Kw = Qw + (size_t)BB * TT * HH;
    unsigned short* Vw = Kw + (size_t)BB * TT * HH;

    convert_k<<<dim3((NXC + 3*128*128 + 255) / 256), 256, 0, stream>>>(x, Wq, Wk, Wv, xb, Wb);
    qkv_gemm<<<dim3(256, 3), 256, 0, stream>>>(xb, Wb, Qw, Kw, Vw);
    attn<<<dim3(1024), 256, 0, stream>>>(Qw, Kw, Vw, (float*)d_out);
}